// Round 4
// baseline (56310.327 us; speedup 1.0000x reference)
//
#include <hip/hip_runtime.h>
#include <hip/hip_bf16.h>
#include <hip/hip_cooperative_groups.h>

namespace cg = cooperative_groups;

typedef __bf16 bf16;
typedef __bf16 bf16x8 __attribute__((ext_vector_type(8)));
typedef float  floatx4 __attribute__((ext_vector_type(4)));
typedef unsigned int uint32;

#define NB   64      // batch
#define NT   240     // timesteps
#define NDIM 512     // audio feature dim
#define NU   1024    // LSTM units
#define NOUT 75      // motion dim
#define NWG  64
#define NTHR 1024

// ring slot strides (elements)
#define HSLOT (64 * 1024)
#define YW    80
#define YSLOT (64 * YW)
#define BW    528
#define BSLOT (64 * BW)

struct Params {
  const float* curr;      // [64,75]
  const float* bias[8];   // enc1,enc2,enc3,fc,dec1,dec2,dec3,out
  const bf16*  pk[8];     // packed weights (B-fragment layout)
  const bf16*  audio_bf;  // [64, 240*512] bf16
  bf16* hr[6];            // h rings [R][64][1024] (enc1..3, dec1..3)
  bf16* ybuf;             // [R][64][80]  (y feedback, cols 75..79 zero)
  bf16* hbot;             // [240][64][528] write-once full-length bottleneck
  uint32* arrv;           // [64*32] per-WG sequence flags (128B spaced)
  uint32* gof;            // (unused, kept for layout)
  float* out;             // [64,240,75]
  int rmask;              // ring depth - 1
  int pmask;              // heavy-sync period - 1
};

__device__ __forceinline__ float sigmoidf_(float x) { return 1.f / (1.f + __expf(-x)); }

// ---- split-group sync ----
// ENC group = WGs 0..31 (flags arrv[0..31]), DEC group = WGs 32..63.
// Lanes 0..31 poll ENC flags against eneed, lanes 32..63 poll DEC flags
// against dneed (0 = statically satisfied). Adaptive backoff: first 8 polls
// at s_sleep(1) (~27ns) for low latency, then s_sleep(16) (~0.43us) to kill
// poll-storm fabric traffic. Bail ~3.5ms/wait -> wrong-but-finishing runs
// stay diagnosable. (s_sleep arg must be a compile-time constant.)
__device__ __forceinline__ void wait_flags(const uint32* __restrict__ arrv,
                                           uint32 eneed, uint32 dneed, int tid)
{
  if ((eneed | dneed) == 0u) return;   // caller provides its own barrier
  if (tid < 64) {
    const uint32 need = (tid < 32) ? eneed : dneed;
    if (need) {
      int spin = 0;
      while (__hip_atomic_load(&arrv[tid * 32], __ATOMIC_RELAXED, __HIP_MEMORY_SCOPE_AGENT) < need) {
        if (spin < 8) __builtin_amdgcn_s_sleep(1);
        else          __builtin_amdgcn_s_sleep(16);
        if (++spin > 8192) break;
      }
    }
  }
  __syncthreads();
}

// Producer side: drain own global stores (per-wave vmcnt, joined by barrier),
// then publish the new sequence number.
__device__ __forceinline__ void post_flag(uint32* __restrict__ arrv, uint32 v, int w, int tid)
{
  asm volatile("s_waitcnt vmcnt(0)" ::: "memory");
  __syncthreads();
  if (tid == 0)
    __hip_atomic_store(&arrv[w * 32], v, __ATOMIC_RELAXED, __HIP_MEMORY_SCOPE_AGENT);
}

// One 16-unit LSTM sub-stage. A = [p0 (B1) | p1 (B2-B1) | p2 (KTOT-B2)].
// ub = unit base (0..1008, mult of 16). 16 waves: g=wid&3 (gate), s=wid>>2 (K-split).
// Weight fragments for the first 8 k-blocks are prefetched BEFORE the flag wait
// (weights constant - no dependency), hiding L3 latency under the sync.
template<int ST0, int B1, int ST1, int B2, int ST2, int KTOT>
__device__ void lstm_cell(const bf16* __restrict__ p0, const bf16* __restrict__ p1,
                          const bf16* __restrict__ p2,
                          const bf16* __restrict__ pack, const float* __restrict__ bias,
                          bf16* __restrict__ hout, float (* __restrict__ cc)[16],
                          float (* __restrict__ zbuf)[64][16], bf16 (* __restrict__ hstage)[16],
                          const uint32* __restrict__ arrv, uint32 eneed, uint32 dneed,
                          int ub, int tid)
{
  const int lane = tid & 63, wid = tid >> 6;
  const int g = wid & 3, s = wid >> 2;
  const int lr = lane & 15, lq = lane >> 4;
  const int n0 = ub + 1024 * g;
  constexpr int NKB = KTOT / 32;   // >= 48 for every lstm stage

  const bf16* wbase = pack + ((size_t)lq * 4096 + (n0 + lr)) * 8;
  auto wld = [&](int kb) { return *(const bf16x8*)(wbase + (size_t)kb * (4 * 4096 * 8)); };

  bf16x8 wf0 = wld(s);      bf16x8 wf1 = wld(s + 4);
  bf16x8 wf2 = wld(s + 8);  bf16x8 wf3 = wld(s + 12);
  bf16x8 wf4 = wld(s + 16); bf16x8 wf5 = wld(s + 20);
  bf16x8 wf6 = wld(s + 24); bf16x8 wf7 = wld(s + 28);

  wait_flags(arrv, eneed, dneed, tid);

  floatx4 c0 = {0.f,0.f,0.f,0.f}, c1 = {0.f,0.f,0.f,0.f};
  floatx4 c2 = {0.f,0.f,0.f,0.f}, c3 = {0.f,0.f,0.f,0.f};

  auto step = [&](bf16x8 bfr, int kb) {
    const int kq = kb * 32 + lq * 8;
    const bf16* ap;
    int st;
    if (kq < B1)      { ap = p0 + lr * ST0 + kq;        st = ST0; }
    else if (kq < B2) { ap = p1 + lr * ST1 + (kq - B1); st = ST1; }
    else              { ap = p2 + lr * ST2 + (kq - B2); st = ST2; }
    bf16x8 x0 = *(const bf16x8*)(ap);
    bf16x8 x1 = *(const bf16x8*)(ap + 16 * st);
    bf16x8 x2 = *(const bf16x8*)(ap + 32 * st);
    bf16x8 x3 = *(const bf16x8*)(ap + 48 * st);
    c0 = __builtin_amdgcn_mfma_f32_16x16x32_bf16(x0, bfr, c0, 0, 0, 0);
    c1 = __builtin_amdgcn_mfma_f32_16x16x32_bf16(x1, bfr, c1, 0, 0, 0);
    c2 = __builtin_amdgcn_mfma_f32_16x16x32_bf16(x2, bfr, c2, 0, 0, 0);
    c3 = __builtin_amdgcn_mfma_f32_16x16x32_bf16(x3, bfr, c3, 0, 0, 0);
  };

  step(wf0, s);      step(wf1, s + 4);
  step(wf2, s + 8);  step(wf3, s + 12);
  step(wf4, s + 16); step(wf5, s + 20);
  step(wf6, s + 24); step(wf7, s + 28);
  for (int kb = s + 32; kb < NKB; kb += 4) step(wld(kb), kb);

  const int slot = s * 4 + g;
  #pragma unroll
  for (int r = 0; r < 4; ++r) {
    zbuf[slot][     lq * 4 + r][lr] = c0[r];
    zbuf[slot][16 + lq * 4 + r][lr] = c1[r];
    zbuf[slot][32 + lq * 4 + r][lr] = c2[r];
    zbuf[slot][48 + lq * 4 + r][lr] = c3[r];
  }
  __syncthreads();
  // pointwise: 1024 threads = 64 rows x 16 units -> hstage (LDS)
  {
    const int m = tid >> 4, u = tid & 15;
    float zi = 0.f, zf = 0.f, zg = 0.f, zo = 0.f;
    #pragma unroll
    for (int ss = 0; ss < 4; ++ss) {
      zi += zbuf[ss * 4 + 0][m][u];
      zf += zbuf[ss * 4 + 1][m][u];
      zg += zbuf[ss * 4 + 2][m][u];
      zo += zbuf[ss * 4 + 3][m][u];
    }
    const int uc = ub + u;
    zi += bias[uc]; zf += bias[NU + uc]; zg += bias[2 * NU + uc]; zo += bias[3 * NU + uc];
    const float cold = cc[m][u];
    const float cn = sigmoidf_(zf) * cold + sigmoidf_(zi) * tanhf(zg);
    cc[m][u] = cn;
    hstage[m][u] = (bf16)(sigmoidf_(zo) * tanhf(cn));
  }
  __syncthreads();
  // agent-scope (write-through) dword stores so other XCDs see fresh data
  if (tid < 512) {
    const int m = tid >> 3, up = tid & 7;
    const uint32 v = *(const uint32*)&hstage[m][2 * up];
    __hip_atomic_store((uint32*)(hout + (size_t)m * NU + ub) + up, v,
                       __ATOMIC_RELAXED, __HIP_MEMORY_SCOPE_AGENT);
  }
}

// Small GEMM (fc / out): z[64,NEFF] = A[64,1024] @ pack. 16 waves: v=wid&3 rows, s=wid>>2 K.
// Exactly 8 k-blocks per wave -> all weights prefetched before the wait.
template<int NEFF>
__device__ void gemm_small(const bf16* __restrict__ a, const bf16* __restrict__ pack,
                           float (* __restrict__ zbuf)[64][16],
                           const uint32* __restrict__ arrv, uint32 eneed, uint32 dneed,
                           int n0, int tid)
{
  const int lane = tid & 63, wid = tid >> 6;
  const int v = wid & 3, s = wid >> 2;
  const int lr = lane & 15, lq = lane >> 4;

  const bf16* wbase = pack + ((size_t)lq * NEFF + (n0 + lr)) * 8;
  auto wld = [&](int kb) { return *(const bf16x8*)(wbase + (size_t)kb * (4 * NEFF * 8)); };

  bf16x8 wf0 = wld(s);      bf16x8 wf1 = wld(s + 4);
  bf16x8 wf2 = wld(s + 8);  bf16x8 wf3 = wld(s + 12);
  bf16x8 wf4 = wld(s + 16); bf16x8 wf5 = wld(s + 20);
  bf16x8 wf6 = wld(s + 24); bf16x8 wf7 = wld(s + 28);

  wait_flags(arrv, eneed, dneed, tid);

  floatx4 c = {0.f,0.f,0.f,0.f};
  const bf16* ab = a + (size_t)(16 * v + lr) * NU;
  auto step = [&](bf16x8 bfr, int kb) {
    bf16x8 x = *(const bf16x8*)(ab + kb * 32 + lq * 8);
    c = __builtin_amdgcn_mfma_f32_16x16x32_bf16(x, bfr, c, 0, 0, 0);
  };
  step(wf0, s);      step(wf1, s + 4);
  step(wf2, s + 8);  step(wf3, s + 12);
  step(wf4, s + 16); step(wf5, s + 20);
  step(wf6, s + 24); step(wf7, s + 28);

  #pragma unroll
  for (int r = 0; r < 4; ++r) zbuf[s][16 * v + lq * 4 + r][lr] = c[r];
  __syncthreads();
}

extern "C" __global__ void __launch_bounds__(NTHR)
dancer_main(Params p)
{
  __shared__ float zbuf[16][64][16];   // 64 KB partial exchange
  __shared__ float cst[3][2][64][16];  // 24 KB persistent c state (3 layers x 2 halves)
  __shared__ bf16  hstage[64][16];     // 2 KB h staging
  cg::grid_group grid = cg::this_grid();
  const int tid = threadIdx.x;
  const int w = blockIdx.x;
  const int gtid = w * NTHR + tid;
  const int rmask = p.rmask, pmask = p.pmask;

  // ---- init: zero flags, zero h ring slot 'rmask', ybuf slot 0 from curr, zero c ----
  if (tid == 0) {
    p.arrv[w * 32] = 0;
    if (w == 0) *p.gof = 0;
  }
  for (int i = gtid; i < 6 * NB * NU; i += NWG * NTHR) {
    const int b = i >> 16, off = i & 65535;
    p.hr[b][(size_t)rmask * HSLOT + off] = (bf16)0.f;
  }
  for (int i = gtid; i < NB * YW; i += NWG * NTHR) {
    const int m = i / YW, c = i - m * YW;
    p.ybuf[i] = (c < NOUT) ? (bf16)p.curr[m * NOUT + c] : (bf16)0.f;
  }
  for (int i = tid; i < 3 * 2 * 64 * 16; i += NTHR) (&cst[0][0][0][0])[i] = 0.f;
  __syncthreads();
  grid.sync();   // full fence once: init writes visible everywhere (incl. L2 inv)

  // Two decoupled groups, one-way coupled through hbot (write-once, 240 slots):
  //   ENC = WGs 0..31: enc1 -> enc2 -> enc3 -> fc      (4 flags/timestep)
  //   DEC = WGs 32..63: dec1 -> dec2 -> dec3 -> out    (4 flags/timestep)
  // ENC never waits on DEC; DEC's dec1(t) waits ENC>=4t+4 (fc(t) done) and
  // DEC>=4t (out(t-1) done). Critical path: 240 x 4 stages instead of 240 x 8.
  // Periodic grid.sync (every pmask+1 steps, < ring depth R) re-couples the
  // groups and flushes caches before any ring-slot reuse -- ENC's max lead is
  // bounded by that cadence, hence hbot full-length needs no backpressure.
  uint32 vc = 0;

  if (w < 32) {
    // ================= ENC group =================
    const int ub0 = 32 * w;
    for (int t = 0; t < NT; ++t) {
      const int st_ = t & rmask;
      const int sp_ = (t - 1) & rmask;
      __syncthreads();  // zbuf/hstage reuse guard

      // enc1: A = [audio_t (512) | h_enc1(t-1) (1024)]; deps statically satisfied
      lstm_cell<NT * NDIM, NDIM, NU, NDIM, NU, NDIM + NU>(
          p.audio_bf + t * NDIM, p.hr[0] + (size_t)sp_ * HSLOT, p.hr[0] + (size_t)sp_ * HSLOT,
          p.pk[0], p.bias[0], p.hr[0] + (size_t)st_ * HSLOT, cst[0][0], zbuf, &hstage[0],
          p.arrv, 0u, 0u, ub0, tid);
      __syncthreads();
      lstm_cell<NT * NDIM, NDIM, NU, NDIM, NU, NDIM + NU>(
          p.audio_bf + t * NDIM, p.hr[0] + (size_t)sp_ * HSLOT, p.hr[0] + (size_t)sp_ * HSLOT,
          p.pk[0], p.bias[0], p.hr[0] + (size_t)st_ * HSLOT, cst[0][1], zbuf, &hstage[0],
          p.arrv, 0u, 0u, ub0 + 16, tid);
      post_flag(p.arrv, ++vc, w, tid);                     // 4t+1

      lstm_cell<NU, NU, NU, NU, NU, 2 * NU>(
          p.hr[0] + (size_t)st_ * HSLOT, p.hr[1] + (size_t)sp_ * HSLOT, p.hr[1] + (size_t)sp_ * HSLOT,
          p.pk[1], p.bias[1], p.hr[1] + (size_t)st_ * HSLOT, cst[1][0], zbuf, &hstage[0],
          p.arrv, vc, 0u, ub0, tid);                       // waits enc1(t)
      __syncthreads();
      lstm_cell<NU, NU, NU, NU, NU, 2 * NU>(
          p.hr[0] + (size_t)st_ * HSLOT, p.hr[1] + (size_t)sp_ * HSLOT, p.hr[1] + (size_t)sp_ * HSLOT,
          p.pk[1], p.bias[1], p.hr[1] + (size_t)st_ * HSLOT, cst[1][1], zbuf, &hstage[0],
          p.arrv, 0u, 0u, ub0 + 16, tid);
      post_flag(p.arrv, ++vc, w, tid);                     // 4t+2

      lstm_cell<NU, NU, NU, NU, NU, 2 * NU>(
          p.hr[1] + (size_t)st_ * HSLOT, p.hr[2] + (size_t)sp_ * HSLOT, p.hr[2] + (size_t)sp_ * HSLOT,
          p.pk[2], p.bias[2], p.hr[2] + (size_t)st_ * HSLOT, cst[2][0], zbuf, &hstage[0],
          p.arrv, vc, 0u, ub0, tid);                       // waits enc2(t)
      __syncthreads();
      lstm_cell<NU, NU, NU, NU, NU, 2 * NU>(
          p.hr[1] + (size_t)st_ * HSLOT, p.hr[2] + (size_t)sp_ * HSLOT, p.hr[2] + (size_t)sp_ * HSLOT,
          p.pk[2], p.bias[2], p.hr[2] + (size_t)st_ * HSLOT, cst[2][1], zbuf, &hstage[0],
          p.arrv, 0u, 0u, ub0 + 16, tid);
      post_flag(p.arrv, ++vc, w, tid);                     // 4t+3

      // fc: _h = tanh(h_enc3 @ fc_W + b) -> hbot[t] (write-once)
      gemm_small<512>(p.hr[2] + (size_t)st_ * HSLOT, p.pk[3], zbuf,
                      p.arrv, vc, 0u, 16 * w, tid);        // waits enc3(t)
      {
        const int m = tid >> 4, u = tid & 15;
        const float z = zbuf[0][m][u] + zbuf[1][m][u] + zbuf[2][m][u] + zbuf[3][m][u]
                        + p.bias[3][16 * w + u];
        hstage[m][u] = (bf16)tanhf(z);
      }
      __syncthreads();
      if (tid < 512) {
        const int m2 = tid >> 3, up = tid & 7;
        const uint32 v = *(const uint32*)&hstage[m2][2 * up];
        __hip_atomic_store((uint32*)(p.hbot + (size_t)t * BSLOT + (size_t)m2 * BW + 16 * w) + up,
                           v, __ATOMIC_RELAXED, __HIP_MEMORY_SCOPE_AGENT);
      }
      post_flag(p.arrv, ++vc, w, tid);                     // 4t+4

      if ((t & pmask) == pmask) grid.sync();
    }
  } else {
    // ================= DEC group =================
    const int wg = w - 32;
    const int ub0 = 32 * wg;
    for (int t = 0; t < NT; ++t) {
      const int st_ = t & rmask;
      const int sp_ = (t - 1) & rmask;
      __syncthreads();  // zbuf/hstage reuse guard

      // dec1: A = [ybuf(t) (80) | hbot[t] (528) | h_dec1(t-1) (1024)], K=1632
      // waits: ENC >= 4t+4 (fc(t) by all ENC WGs), DEC >= 4t (out(t-1) by all DEC)
      lstm_cell<YW, YW, BW, YW + BW, NU, YW + BW + NU>(
          p.ybuf + (size_t)st_ * YSLOT, p.hbot + (size_t)t * BSLOT, p.hr[3] + (size_t)sp_ * HSLOT,
          p.pk[4], p.bias[4], p.hr[3] + (size_t)st_ * HSLOT, cst[0][0], zbuf, &hstage[0],
          p.arrv, (uint32)(4 * t + 4), vc, ub0, tid);
      __syncthreads();
      lstm_cell<YW, YW, BW, YW + BW, NU, YW + BW + NU>(
          p.ybuf + (size_t)st_ * YSLOT, p.hbot + (size_t)t * BSLOT, p.hr[3] + (size_t)sp_ * HSLOT,
          p.pk[4], p.bias[4], p.hr[3] + (size_t)st_ * HSLOT, cst[0][1], zbuf, &hstage[0],
          p.arrv, 0u, 0u, ub0 + 16, tid);
      post_flag(p.arrv, ++vc, w, tid);                     // 4t+1

      lstm_cell<NU, NU, NU, NU, NU, 2 * NU>(
          p.hr[3] + (size_t)st_ * HSLOT, p.hr[4] + (size_t)sp_ * HSLOT, p.hr[4] + (size_t)sp_ * HSLOT,
          p.pk[5], p.bias[5], p.hr[4] + (size_t)st_ * HSLOT, cst[1][0], zbuf, &hstage[0],
          p.arrv, 0u, vc, ub0, tid);                       // waits dec1(t)
      __syncthreads();
      lstm_cell<NU, NU, NU, NU, NU, 2 * NU>(
          p.hr[3] + (size_t)st_ * HSLOT, p.hr[4] + (size_t)sp_ * HSLOT, p.hr[4] + (size_t)sp_ * HSLOT,
          p.pk[5], p.bias[5], p.hr[4] + (size_t)st_ * HSLOT, cst[1][1], zbuf, &hstage[0],
          p.arrv, 0u, 0u, ub0 + 16, tid);
      post_flag(p.arrv, ++vc, w, tid);                     // 4t+2

      lstm_cell<NU, NU, NU, NU, NU, 2 * NU>(
          p.hr[4] + (size_t)st_ * HSLOT, p.hr[5] + (size_t)sp_ * HSLOT, p.hr[5] + (size_t)sp_ * HSLOT,
          p.pk[6], p.bias[6], p.hr[5] + (size_t)st_ * HSLOT, cst[2][0], zbuf, &hstage[0],
          p.arrv, 0u, vc, ub0, tid);                       // waits dec2(t)
      __syncthreads();
      lstm_cell<NU, NU, NU, NU, NU, 2 * NU>(
          p.hr[4] + (size_t)st_ * HSLOT, p.hr[5] + (size_t)sp_ * HSLOT, p.hr[5] + (size_t)sp_ * HSLOT,
          p.pk[6], p.bias[6], p.hr[5] + (size_t)st_ * HSLOT, cst[2][1], zbuf, &hstage[0],
          p.arrv, 0u, 0u, ub0 + 16, tid);
      post_flag(p.arrv, ++vc, w, tid);                     // 4t+3

      // out: y = elu(h_dec3 @ out_W + b) -> d_out and ybuf slot t+1
      // (DEC WGs 0..4 of the group; 5..31 post and charge into dec1(t+1))
      if (wg < 5) {
        gemm_small<80>(p.hr[5] + (size_t)st_ * HSLOT, p.pk[7], zbuf,
                       p.arrv, 0u, vc, 16 * wg, tid);      // waits dec3(t)
        const int m = tid >> 4, u = tid & 15;
        const int n = 16 * wg + u;
        float y = 0.f;
        if (n < NOUT) {
          const float z = zbuf[0][m][u] + zbuf[1][m][u] + zbuf[2][m][u] + zbuf[3][m][u]
                          + p.bias[7][n];
          y = (z > 0.f) ? z : (__expf(z) - 1.f);
          p.out[(m * NT + t) * NOUT + n] = y;
        }
        hstage[m][u] = (bf16)y;
        __syncthreads();
        if (tid < 512) {
          const int m2 = tid >> 3, up = tid & 7;
          const uint32 v = *(const uint32*)&hstage[m2][2 * up];
          const size_t sn = (size_t)((t + 1) & rmask) * YSLOT;
          __hip_atomic_store((uint32*)(p.ybuf + sn + (size_t)m2 * YW + 16 * wg) + up,
                             v, __ATOMIC_RELAXED, __HIP_MEMORY_SCOPE_AGENT);
        }
      }
      post_flag(p.arrv, ++vc, w, tid);                     // 4t+4

      if ((t & pmask) == pmask) grid.sync();
    }
  }
}

// ---- pre-kernels ----

__global__ void pack_w(const float* __restrict__ Wx, const float* __restrict__ Wh,
                       int Kx, int KhStart, int Keff, int N, int Neff,
                       bf16* __restrict__ dst)
{
  const int idx = blockIdx.x * blockDim.x + threadIdx.x;
  const int nkb = Keff >> 3;
  const int total = nkb * Neff;
  if (idx >= total) return;
  const int kb = idx / Neff;
  const int n  = idx - kb * Neff;
  bf16x8 o;
  #pragma unroll
  for (int j = 0; j < 8; ++j) {
    const int k = kb * 8 + j;
    float v = 0.f;
    if (n < N) {
      if (k < Kx) v = Wx[(size_t)k * N + n];
      else if (k >= KhStart) v = Wh[(size_t)(k - KhStart) * N + n];
    }
    o[j] = (bf16)v;
  }
  *(bf16x8*)(dst + ((size_t)kb * Neff + n) * 8) = o;
}

// dec1: rows 0..74 = Wx[0..74] (y), 75..79 = 0, 80..591 = Wx[75..586] (_h),
//       592..607 = 0, 608..1631 = Wh.  K=1632, N=4096.
__global__ void pack_dec1(const float* __restrict__ Wx, const float* __restrict__ Wh,
                          bf16* __restrict__ dst)
{
  const int idx = blockIdx.x * blockDim.x + threadIdx.x;
  const int total = (1632 >> 3) * 4096;
  if (idx >= total) return;
  const int kb = idx >> 12;
  const int n  = idx & 4095;
  bf16x8 o;
  #pragma unroll
  for (int j = 0; j < 8; ++j) {
    const int k = kb * 8 + j;
    float v = 0.f;
    if (k < 75)                  v = Wx[(size_t)k * 4096 + n];
    else if (k >= 80 && k < 592) v = Wx[(size_t)(k - 5) * 4096 + n];
    else if (k >= 608)           v = Wh[(size_t)(k - 608) * 4096 + n];
    o[j] = (bf16)v;
  }
  *(bf16x8*)(dst + ((size_t)kb * 4096 + n) * 8) = o;
}

__global__ void cvt_bf16(const float* __restrict__ src, bf16* __restrict__ dst, int n)
{
  const int i = blockIdx.x * blockDim.x + threadIdx.x;
  if (i < n) dst[i] = (bf16)src[i];
}

extern "C" void kernel_launch(void* const* d_in, const int* in_sizes, int n_in,
                              void* d_out, int out_size, void* d_ws, size_t ws_size,
                              hipStream_t stream)
{
  (void)in_sizes; (void)n_in; (void)out_size;

  const float* audio = (const float*)d_in[0];
  const float* curr  = (const float*)d_in[1];
  const float* Wp[8][2] = {
    { (const float*)d_in[2],  (const float*)d_in[3]  },  // enc1
    { (const float*)d_in[5],  (const float*)d_in[6]  },  // enc2
    { (const float*)d_in[8],  (const float*)d_in[9]  },  // enc3
    { (const float*)d_in[11], nullptr                },  // fc
    { (const float*)d_in[13], (const float*)d_in[14] },  // dec1
    { (const float*)d_in[16], (const float*)d_in[17] },  // dec2
    { (const float*)d_in[19], (const float*)d_in[20] },  // dec3
    { (const float*)d_in[22], nullptr                },  // out
  };
  const float* bias[8] = {
    (const float*)d_in[4],  (const float*)d_in[7],  (const float*)d_in[10],
    (const float*)d_in[12], (const float*)d_in[15], (const float*)d_in[18],
    (const float*)d_in[21], (const float*)d_in[23],
  };

  // {Kx, KhStart, Keff, N, Neff}; dec1 handled by pack_dec1
  const int geo[8][5] = {
    { 512,  512,  1536, 4096, 4096 },  // enc1
    { 1024, 1024, 2048, 4096, 4096 },  // enc2
    { 1024, 1024, 2048, 4096, 4096 },  // enc3
    { 1024, 1024, 1024, 512,  512  },  // fc
    { 0,    0,    1632, 4096, 4096 },  // dec1 (custom)
    { 1024, 1024, 2048, 4096, 4096 },  // dec2
    { 1024, 1024, 2048, 4096, 4096 },  // dec3
    { 1024, 1024, 1024, 75,   80   },  // out
  };

  char* ws = (char*)d_ws;
  size_t off = 0;
  auto take = [&](size_t bytes) -> char* {
    char* p = ws + off;
    off = (off + bytes + 255) & ~(size_t)255;
    return p;
  };

  bf16* audio_bf = (bf16*)take((size_t)NB * NT * NDIM * 2);
  bf16* pk[8];
  for (int i = 0; i < 8; ++i) pk[i] = (bf16*)take((size_t)geo[i][2] * geo[i][4] * 2);
  uint32* arrv = (uint32*)take(64 * 32 * sizeof(uint32));
  uint32* gof  = (uint32*)take(256);
  bf16* hbot = (bf16*)take((size_t)NT * BSLOT * 2);   // full-length, write-once

  // pick h-ring depth that fits ws
  const size_t slot_bytes = (size_t)6 * HSLOT * 2 + (size_t)YSLOT * 2 + 4096;
  int R = 32;
  while (R > 4 && off + (size_t)R * slot_bytes + (1 << 20) > ws_size) R >>= 1;

  bf16* hr[6];
  for (int i = 0; i < 6; ++i) hr[i] = (bf16*)take((size_t)R * HSLOT * 2);
  bf16* ybuf = (bf16*)take((size_t)R * YSLOT * 2);

  {
    const int n = NB * NT * NDIM;
    cvt_bf16<<<(n + 255) / 256, 256, 0, stream>>>(audio, audio_bf, n);
  }
  for (int i = 0; i < 8; ++i) {
    if (i == 4) {
      const int total = (1632 >> 3) * 4096;
      pack_dec1<<<(total + 255) / 256, 256, 0, stream>>>(Wp[4][0], Wp[4][1], pk[4]);
    } else {
      const int total = (geo[i][2] >> 3) * geo[i][4];
      pack_w<<<(total + 255) / 256, 256, 0, stream>>>(
          Wp[i][0], Wp[i][1], geo[i][0], geo[i][1], geo[i][2], geo[i][3], geo[i][4], pk[i]);
    }
  }

  Params P;
  P.curr = curr;
  for (int i = 0; i < 8; ++i) { P.bias[i] = bias[i]; P.pk[i] = pk[i]; }
  P.audio_bf = audio_bf;
  for (int i = 0; i < 6; ++i) P.hr[i] = hr[i];
  P.ybuf = ybuf;
  P.hbot = hbot;
  P.arrv = arrv;
  P.gof = gof;
  P.out = (float*)d_out;
  P.rmask = R - 1;
  P.pmask = (R >> 1) - 1;

  void* args[] = { &P };
  (void)hipLaunchCooperativeKernel(reinterpret_cast<void*>(dancer_main),
                                   dim3(NWG), dim3(NTHR), args, 0, stream);
}

// Round 5
// 55331.586 us; speedup vs baseline: 1.0177x; 1.0177x over previous
//
#include <hip/hip_runtime.h>
#include <hip/hip_bf16.h>
#include <hip/hip_cooperative_groups.h>

namespace cg = cooperative_groups;

typedef __bf16 bf16;
typedef __bf16 bf16x8 __attribute__((ext_vector_type(8)));
typedef float  floatx4 __attribute__((ext_vector_type(4)));
typedef unsigned int uint32;

#define NB   64      // batch
#define NT   240     // timesteps
#define NDIM 512     // audio feature dim
#define NU   1024    // LSTM units
#define NOUT 75      // motion dim
#define NWG  64
#define NTHR 1024

// ring slot strides (elements)
#define HSLOT (64 * 1024)
#define YW    80
#define YSLOT (64 * YW)
#define BW    528
#define BSLOT (64 * BW)

struct Params {
  const float* curr;      // [64,75]
  const float* bias[8];   // enc1,enc2,enc3,fc,dec1,dec2,dec3,out
  const bf16*  pk[8];     // packed weights (B-fragment layout)
  const bf16*  audio_bf;  // [64, 240*512] bf16
  bf16* hr[6];            // h rings [R][64][1024] (enc1..3, dec1..3)
  bf16* ybuf;             // [R][64][80]  (y feedback, cols 75..79 zero)
  bf16* hbot;             // [R][64][528] (_h bottleneck, cols 512..527 junk*0-weight)
  uint32* arrv;           // [64*32] arrival flags (128B spaced)
  uint32* gof;            // go flag
  float* out;             // [64,240,75]
  int rmask;              // ring depth - 1
  int pmask;              // heavy-sync period - 1
};

__device__ __forceinline__ float sigmoidf_(float x) { return 1.f / (1.f + __expf(-x)); }

// ---- cache-friendly grid barrier (two-hop; best measured variant) ----
// Caller's global stores are made visible (vmcnt drain) before arrival.
__device__ __forceinline__ void gbar(uint32* arrv, uint32* gof, uint32 sc, int w, int tid)
{
  asm volatile("s_waitcnt vmcnt(0)" ::: "memory");
  __syncthreads();
  if (w == 0) {
    if (tid == 0)
      __hip_atomic_store(&arrv[0], sc, __ATOMIC_RELAXED, __HIP_MEMORY_SCOPE_AGENT);
    if (tid < NWG) {
      int spin = 0;
      while (__hip_atomic_load(&arrv[tid * 32], __ATOMIC_RELAXED, __HIP_MEMORY_SCOPE_AGENT) < sc) {
        __builtin_amdgcn_s_sleep(1);
        if (++spin > (1 << 24)) break;  // bail instead of hard hang
      }
    }
    __syncthreads();
    if (tid == 0)
      __hip_atomic_store(gof, sc, __ATOMIC_RELAXED, __HIP_MEMORY_SCOPE_AGENT);
  } else {
    if (tid == 0) {
      __hip_atomic_store(&arrv[w * 32], sc, __ATOMIC_RELAXED, __HIP_MEMORY_SCOPE_AGENT);
      int spin = 0;
      while (__hip_atomic_load(gof, __ATOMIC_RELAXED, __HIP_MEMORY_SCOPE_AGENT) < sc) {
        __builtin_amdgcn_s_sleep(1);
        if (++spin > (1 << 24)) break;
      }
    }
    __syncthreads();
  }
}

// One LSTM cell stage. A = [p0 (B1) | p1 (B2-B1) | p2 (KTOT-B2)], all widths mult of 8.
// WG w owns units [16w,16w+16). 16 waves: g=wid&3 (gate), s=wid>>2 (K-split).
// Inner loop: ALL weight fragments preloaded into registers (one latency for the
// whole set), A-fragments in a fully-unrolled 2-deep register double-buffer so
// iteration i+1's loads are in flight while iteration i's MFMAs run.
template<int ST0, int B1, int ST1, int B2, int ST2, int KTOT>
__device__ void lstm_cell(const bf16* __restrict__ p0, const bf16* __restrict__ p1,
                          const bf16* __restrict__ p2,
                          const bf16* __restrict__ pack, const float* __restrict__ bias,
                          bf16* __restrict__ hout, float (* __restrict__ cc)[16],
                          float (* __restrict__ zbuf)[64][16], bf16 (* __restrict__ hstage)[16],
                          int w, int tid)
{
  const int lane = tid & 63, wid = tid >> 6;
  const int g = wid & 3, s = wid >> 2;
  const int lr = lane & 15, lq = lane >> 4;
  const int n0 = 16 * w + 1024 * g;
  constexpr int NKB = KTOT / 32;          // k-blocks total
  constexpr int NITER = (NKB + 3) / 4;    // per-wave iterations (kb = s + 4i)

  const bf16* wbase = pack + ((size_t)lq * 4096 + (n0 + lr)) * 8;

  // ---- preload ALL weight fragments (independent loads, all in flight) ----
  bf16x8 wreg[NITER];
  #pragma unroll
  for (int i = 0; i < NITER; ++i) {
    int kb = s + 4 * i;
    if constexpr (NKB % 4 != 0) { if (kb >= NKB) kb = s; }
    wreg[i] = *(const bf16x8*)(wbase + (size_t)kb * (4 * 4096 * 8));
  }
  if constexpr (NKB % 4 != 0) {
    if (s + 4 * (NITER - 1) >= NKB) {
      #pragma unroll
      for (int j = 0; j < 8; ++j) wreg[NITER - 1][j] = (bf16)0.f;
    }
  }

  // A-fragment address helpers (segment select per lane; boundaries mult of 8)
  auto aaddr = [&](int kb) -> const bf16* {
    const int kq = kb * 32 + lq * 8;
    if (kq < B1)      return p0 + lr * ST0 + kq;
    else if (kq < B2) return p1 + lr * ST1 + (kq - B1);
    else              return p2 + lr * ST2 + (kq - B2);
  };
  auto astr = [&](int kb) -> int {
    const int kq = kb * 32 + lq * 8;
    return (kq < B1) ? ST0 : ((kq < B2) ? ST1 : ST2);
  };

  floatx4 c0 = {0.f,0.f,0.f,0.f}, c1 = {0.f,0.f,0.f,0.f};
  floatx4 c2 = {0.f,0.f,0.f,0.f}, c3 = {0.f,0.f,0.f,0.f};

  bf16x8 xa[2][4];
  // prologue: iteration 0 A-loads (kb = s always < NKB since NKB >= 4)
  {
    const bf16* ap = aaddr(s); const int st_ = astr(s);
    xa[0][0] = *(const bf16x8*)(ap);
    xa[0][1] = *(const bf16x8*)(ap + 16 * st_);
    xa[0][2] = *(const bf16x8*)(ap + 32 * st_);
    xa[0][3] = *(const bf16x8*)(ap + 48 * st_);
  }
  #pragma unroll
  for (int i = 0; i < NITER; ++i) {
    const int cur = i & 1, nxt = cur ^ 1;
    if (i + 1 < NITER) {
      int kb = s + 4 * (i + 1);
      if constexpr (NKB % 4 != 0) { if (kb >= NKB) kb = s; }  // tail: zero weight kills it
      const bf16* ap = aaddr(kb); const int st_ = astr(kb);
      xa[nxt][0] = *(const bf16x8*)(ap);
      xa[nxt][1] = *(const bf16x8*)(ap + 16 * st_);
      xa[nxt][2] = *(const bf16x8*)(ap + 32 * st_);
      xa[nxt][3] = *(const bf16x8*)(ap + 48 * st_);
    }
    c0 = __builtin_amdgcn_mfma_f32_16x16x32_bf16(xa[cur][0], wreg[i], c0, 0, 0, 0);
    c1 = __builtin_amdgcn_mfma_f32_16x16x32_bf16(xa[cur][1], wreg[i], c1, 0, 0, 0);
    c2 = __builtin_amdgcn_mfma_f32_16x16x32_bf16(xa[cur][2], wreg[i], c2, 0, 0, 0);
    c3 = __builtin_amdgcn_mfma_f32_16x16x32_bf16(xa[cur][3], wreg[i], c3, 0, 0, 0);
  }

  const int slot = s * 4 + g;
  #pragma unroll
  for (int r = 0; r < 4; ++r) {
    zbuf[slot][     lq * 4 + r][lr] = c0[r];
    zbuf[slot][16 + lq * 4 + r][lr] = c1[r];
    zbuf[slot][32 + lq * 4 + r][lr] = c2[r];
    zbuf[slot][48 + lq * 4 + r][lr] = c3[r];
  }
  __syncthreads();
  // pointwise: 1024 threads = 64 rows x 16 units -> hstage (LDS)
  {
    const int m = tid >> 4, u = tid & 15;
    float zi = 0.f, zf = 0.f, zg = 0.f, zo = 0.f;
    #pragma unroll
    for (int ss = 0; ss < 4; ++ss) {
      zi += zbuf[ss * 4 + 0][m][u];
      zf += zbuf[ss * 4 + 1][m][u];
      zg += zbuf[ss * 4 + 2][m][u];
      zo += zbuf[ss * 4 + 3][m][u];
    }
    const int uc = 16 * w + u;
    zi += bias[uc]; zf += bias[NU + uc]; zg += bias[2 * NU + uc]; zo += bias[3 * NU + uc];
    const float cold = cc[m][u];
    const float cn = sigmoidf_(zf) * cold + sigmoidf_(zi) * tanhf(zg);
    cc[m][u] = cn;
    hstage[m][u] = (bf16)(sigmoidf_(zo) * tanhf(cn));
  }
  __syncthreads();
  // agent-scope (write-through) dword stores so other XCDs see fresh data
  if (tid < 512) {
    const int m = tid >> 3, up = tid & 7;
    const uint32 v = *(const uint32*)&hstage[m][2 * up];
    __hip_atomic_store((uint32*)(hout + (size_t)m * NU + 16 * w) + up, v,
                       __ATOMIC_RELAXED, __HIP_MEMORY_SCOPE_AGENT);
  }
}

// Small GEMM (fc / out): z[64,NEFF] = A[64,1024] @ pack. 16 waves: v=wid&3 rows, s=wid>>2 K.
// 8 k-blocks/wave: all weights preloaded, A in 2-deep register pipeline.
template<int NEFF>
__device__ void gemm_small(const bf16* __restrict__ a, const bf16* __restrict__ pack,
                           float (* __restrict__ zbuf)[64][16], int w, int tid)
{
  const int lane = tid & 63, wid = tid >> 6;
  const int v = wid & 3, s = wid >> 2;
  const int lr = lane & 15, lq = lane >> 4;
  const int n0 = 16 * w;

  const bf16* wbase = pack + ((size_t)lq * NEFF + (n0 + lr)) * 8;

  bf16x8 wreg[8];
  #pragma unroll
  for (int i = 0; i < 8; ++i)
    wreg[i] = *(const bf16x8*)(wbase + (size_t)(s + 4 * i) * (4 * NEFF * 8));

  floatx4 c = {0.f,0.f,0.f,0.f};
  const bf16* ab = a + (size_t)(16 * v + lr) * NU;

  bf16x8 xa[2];
  xa[0] = *(const bf16x8*)(ab + s * 32 + lq * 8);
  #pragma unroll
  for (int i = 0; i < 8; ++i) {
    const int cur = i & 1, nxt = cur ^ 1;
    if (i + 1 < 8)
      xa[nxt] = *(const bf16x8*)(ab + (s + 4 * (i + 1)) * 32 + lq * 8);
    c = __builtin_amdgcn_mfma_f32_16x16x32_bf16(xa[cur], wreg[i], c, 0, 0, 0);
  }

  #pragma unroll
  for (int r = 0; r < 4; ++r) zbuf[s][16 * v + lq * 4 + r][lr] = c[r];
  __syncthreads();
}

extern "C" __global__ void __launch_bounds__(NTHR, 1)
dancer_main(Params p)
{
  __shared__ float zbuf[16][64][16];  // 64 KB partial exchange
  __shared__ float cst[6][64][16];    // 24 KB persistent c state
  __shared__ bf16  hstage[64][16];    // 2 KB h staging
  cg::grid_group grid = cg::this_grid();
  const int tid = threadIdx.x;
  const int w = blockIdx.x;
  const int gtid = w * NTHR + tid;
  const int rmask = p.rmask, pmask = p.pmask;

  // ---- init: zero flags, zero h ring slot 'rmask', ybuf slot 0 from curr, zero c ----
  if (tid == 0) {
    p.arrv[w * 32] = 0;
    if (w == 0) *p.gof = 0;
  }
  for (int i = gtid; i < 6 * NB * NU; i += NWG * NTHR) {
    const int b = i >> 16, off = i & 65535;
    p.hr[b][(size_t)rmask * HSLOT + off] = (bf16)0.f;
  }
  for (int i = gtid; i < NB * YW; i += NWG * NTHR) {
    const int m = i / YW, c = i - m * YW;
    p.ybuf[i] = (c < NOUT) ? (bf16)p.curr[m * NOUT + c] : (bf16)0.f;
  }
  for (int i = tid; i < 6 * 64 * 16; i += NTHR) (&cst[0][0][0])[i] = 0.f;
  __syncthreads();
  grid.sync();   // full fence once: init writes visible everywhere

  uint32 sc = 1;
  for (int t = 0; t < NT; ++t) {
    const int st_ = t & rmask;
    const int sp_ = (t - 1) & rmask;
    __syncthreads();  // protect zbuf/hstage reuse against previous stage's readers

    // enc1: A = [audio_t (512) | h_enc1(t-1) (1024)]
    lstm_cell<NT * NDIM, NDIM, NU, NDIM, NU, NDIM + NU>(
        p.audio_bf + t * NDIM, p.hr[0] + (size_t)sp_ * HSLOT, p.hr[0] + (size_t)sp_ * HSLOT,
        p.pk[0], p.bias[0], p.hr[0] + (size_t)st_ * HSLOT, cst[0], zbuf, &hstage[0], w, tid);
    gbar(p.arrv, p.gof, sc++, w, tid);

    lstm_cell<NU, NU, NU, NU, NU, 2 * NU>(
        p.hr[0] + (size_t)st_ * HSLOT, p.hr[1] + (size_t)sp_ * HSLOT, p.hr[1] + (size_t)sp_ * HSLOT,
        p.pk[1], p.bias[1], p.hr[1] + (size_t)st_ * HSLOT, cst[1], zbuf, &hstage[0], w, tid);
    gbar(p.arrv, p.gof, sc++, w, tid);

    lstm_cell<NU, NU, NU, NU, NU, 2 * NU>(
        p.hr[1] + (size_t)st_ * HSLOT, p.hr[2] + (size_t)sp_ * HSLOT, p.hr[2] + (size_t)sp_ * HSLOT,
        p.pk[2], p.bias[2], p.hr[2] + (size_t)st_ * HSLOT, cst[2], zbuf, &hstage[0], w, tid);
    gbar(p.arrv, p.gof, sc++, w, tid);

    // fc: _h = tanh(h_enc3 @ fc_W + b) -> hbot slot t
    if (w < 32) {
      gemm_small<512>(p.hr[2] + (size_t)st_ * HSLOT, p.pk[3], zbuf, w, tid);
      const int m = tid >> 4, u = tid & 15;
      const float z = zbuf[0][m][u] + zbuf[1][m][u] + zbuf[2][m][u] + zbuf[3][m][u]
                      + p.bias[3][16 * w + u];
      hstage[m][u] = (bf16)tanhf(z);
      __syncthreads();
      if (tid < 512) {
        const int m2 = tid >> 3, up = tid & 7;
        const uint32 v = *(const uint32*)&hstage[m2][2 * up];
        __hip_atomic_store((uint32*)(p.hbot + (size_t)st_ * BSLOT + (size_t)m2 * BW + 16 * w) + up,
                           v, __ATOMIC_RELAXED, __HIP_MEMORY_SCOPE_AGENT);
      }
    }
    gbar(p.arrv, p.gof, sc++, w, tid);

    // dec1: A = [ybuf slot t (80) | hbot slot t (528) | h_dec1(t-1) (1024)], K=1632
    lstm_cell<YW, YW, BW, YW + BW, NU, YW + BW + NU>(
        p.ybuf + (size_t)st_ * YSLOT, p.hbot + (size_t)st_ * BSLOT, p.hr[3] + (size_t)sp_ * HSLOT,
        p.pk[4], p.bias[4], p.hr[3] + (size_t)st_ * HSLOT, cst[3], zbuf, &hstage[0], w, tid);
    gbar(p.arrv, p.gof, sc++, w, tid);

    lstm_cell<NU, NU, NU, NU, NU, 2 * NU>(
        p.hr[3] + (size_t)st_ * HSLOT, p.hr[4] + (size_t)sp_ * HSLOT, p.hr[4] + (size_t)sp_ * HSLOT,
        p.pk[5], p.bias[5], p.hr[4] + (size_t)st_ * HSLOT, cst[4], zbuf, &hstage[0], w, tid);
    gbar(p.arrv, p.gof, sc++, w, tid);

    lstm_cell<NU, NU, NU, NU, NU, 2 * NU>(
        p.hr[4] + (size_t)st_ * HSLOT, p.hr[5] + (size_t)sp_ * HSLOT, p.hr[5] + (size_t)sp_ * HSLOT,
        p.pk[6], p.bias[6], p.hr[5] + (size_t)st_ * HSLOT, cst[5], zbuf, &hstage[0], w, tid);
    gbar(p.arrv, p.gof, sc++, w, tid);

    // out: y = elu(h_dec3 @ out_W + b) -> d_out and ybuf slot t+1 (no barrier:
    // covered by next step's chain before dec1 reads it)
    if (w < 5) {
      gemm_small<80>(p.hr[5] + (size_t)st_ * HSLOT, p.pk[7], zbuf, w, tid);
      const int m = tid >> 4, u = tid & 15;
      const int n = 16 * w + u;
      float y = 0.f;
      if (n < NOUT) {
        const float z = zbuf[0][m][u] + zbuf[1][m][u] + zbuf[2][m][u] + zbuf[3][m][u]
                        + p.bias[7][n];
        y = (z > 0.f) ? z : (__expf(z) - 1.f);
        p.out[(m * NT + t) * NOUT + n] = y;
      }
      hstage[m][u] = (bf16)y;
      __syncthreads();
      if (tid < 512) {
        const int m2 = tid >> 3, up = tid & 7;
        const uint32 v = *(const uint32*)&hstage[m2][2 * up];
        const size_t sn = (size_t)((t + 1) & rmask) * YSLOT;
        __hip_atomic_store((uint32*)(p.ybuf + sn + (size_t)m2 * YW + 16 * w) + up,
                           v, __ATOMIC_RELAXED, __HIP_MEMORY_SCOPE_AGENT);
      }
    }
    // periodic full sync: flush any cached ring lines before slot reuse
    if ((t & pmask) == pmask) grid.sync();
  }
}

// ---- pre-kernels ----

__global__ void pack_w(const float* __restrict__ Wx, const float* __restrict__ Wh,
                       int Kx, int KhStart, int Keff, int N, int Neff,
                       bf16* __restrict__ dst)
{
  const int idx = blockIdx.x * blockDim.x + threadIdx.x;
  const int nkb = Keff >> 3;
  const int total = nkb * Neff;
  if (idx >= total) return;
  const int kb = idx / Neff;
  const int n  = idx - kb * Neff;
  bf16x8 o;
  #pragma unroll
  for (int j = 0; j < 8; ++j) {
    const int k = kb * 8 + j;
    float v = 0.f;
    if (n < N) {
      if (k < Kx) v = Wx[(size_t)k * N + n];
      else if (k >= KhStart) v = Wh[(size_t)(k - KhStart) * N + n];
    }
    o[j] = (bf16)v;
  }
  *(bf16x8*)(dst + ((size_t)kb * Neff + n) * 8) = o;
}

// dec1: rows 0..74 = Wx[0..74] (y), 75..79 = 0, 80..591 = Wx[75..586] (_h),
//       592..607 = 0, 608..1631 = Wh.  K=1632, N=4096.
__global__ void pack_dec1(const float* __restrict__ Wx, const float* __restrict__ Wh,
                          bf16* __restrict__ dst)
{
  const int idx = blockIdx.x * blockDim.x + threadIdx.x;
  const int total = (1632 >> 3) * 4096;
  if (idx >= total) return;
  const int kb = idx >> 12;
  const int n  = idx & 4095;
  bf16x8 o;
  #pragma unroll
  for (int j = 0; j < 8; ++j) {
    const int k = kb * 8 + j;
    float v = 0.f;
    if (k < 75)                  v = Wx[(size_t)k * 4096 + n];
    else if (k >= 80 && k < 592) v = Wx[(size_t)(k - 5) * 4096 + n];
    else if (k >= 608)           v = Wh[(size_t)(k - 608) * 4096 + n];
    o[j] = (bf16)v;
  }
  *(bf16x8*)(dst + ((size_t)kb * 4096 + n) * 8) = o;
}

__global__ void cvt_bf16(const float* __restrict__ src, bf16* __restrict__ dst, int n)
{
  const int i = blockIdx.x * blockDim.x + threadIdx.x;
  if (i < n) dst[i] = (bf16)src[i];
}

extern "C" void kernel_launch(void* const* d_in, const int* in_sizes, int n_in,
                              void* d_out, int out_size, void* d_ws, size_t ws_size,
                              hipStream_t stream)
{
  (void)in_sizes; (void)n_in; (void)out_size;

  const float* audio = (const float*)d_in[0];
  const float* curr  = (const float*)d_in[1];
  const float* Wp[8][2] = {
    { (const float*)d_in[2],  (const float*)d_in[3]  },  // enc1
    { (const float*)d_in[5],  (const float*)d_in[6]  },  // enc2
    { (const float*)d_in[8],  (const float*)d_in[9]  },  // enc3
    { (const float*)d_in[11], nullptr                },  // fc
    { (const float*)d_in[13], (const float*)d_in[14] },  // dec1
    { (const float*)d_in[16], (const float*)d_in[17] },  // dec2
    { (const float*)d_in[19], (const float*)d_in[20] },  // dec3
    { (const float*)d_in[22], nullptr                },  // out
  };
  const float* bias[8] = {
    (const float*)d_in[4],  (const float*)d_in[7],  (const float*)d_in[10],
    (const float*)d_in[12], (const float*)d_in[15], (const float*)d_in[18],
    (const float*)d_in[21], (const float*)d_in[23],
  };

  // {Kx, KhStart, Keff, N, Neff}; dec1 handled by pack_dec1
  const int geo[8][5] = {
    { 512,  512,  1536, 4096, 4096 },  // enc1
    { 1024, 1024, 2048, 4096, 4096 },  // enc2
    { 1024, 1024, 2048, 4096, 4096 },  // enc3
    { 1024, 1024, 1024, 512,  512  },  // fc
    { 0,    0,    1632, 4096, 4096 },  // dec1 (custom)
    { 1024, 1024, 2048, 4096, 4096 },  // dec2
    { 1024, 1024, 2048, 4096, 4096 },  // dec3
    { 1024, 1024, 1024, 75,   80   },  // out
  };

  char* ws = (char*)d_ws;
  size_t off = 0;
  auto take = [&](size_t bytes) -> char* {
    char* p = ws + off;
    off = (off + bytes + 255) & ~(size_t)255;
    return p;
  };

  bf16* audio_bf = (bf16*)take((size_t)NB * NT * NDIM * 2);
  bf16* pk[8];
  for (int i = 0; i < 8; ++i) pk[i] = (bf16*)take((size_t)geo[i][2] * geo[i][4] * 2);
  uint32* arrv = (uint32*)take(64 * 32 * sizeof(uint32));
  uint32* gof  = (uint32*)take(256);

  // pick ring depth that fits ws
  const size_t slot_bytes = (size_t)6 * HSLOT * 2 + (size_t)YSLOT * 2 + (size_t)BSLOT * 2 + 4096;
  int R = 32;
  while (R > 4 && off + (size_t)R * slot_bytes + (1 << 20) > ws_size) R >>= 1;

  bf16* hr[6];
  for (int i = 0; i < 6; ++i) hr[i] = (bf16*)take((size_t)R * HSLOT * 2);
  bf16* ybuf = (bf16*)take((size_t)R * YSLOT * 2);
  bf16* hbot = (bf16*)take((size_t)R * BSLOT * 2);

  {
    const int n = NB * NT * NDIM;
    cvt_bf16<<<(n + 255) / 256, 256, 0, stream>>>(audio, audio_bf, n);
  }
  for (int i = 0; i < 8; ++i) {
    if (i == 4) {
      const int total = (1632 >> 3) * 4096;
      pack_dec1<<<(total + 255) / 256, 256, 0, stream>>>(Wp[4][0], Wp[4][1], pk[4]);
    } else {
      const int total = (geo[i][2] >> 3) * geo[i][4];
      pack_w<<<(total + 255) / 256, 256, 0, stream>>>(
          Wp[i][0], Wp[i][1], geo[i][0], geo[i][1], geo[i][2], geo[i][3], geo[i][4], pk[i]);
    }
  }

  Params P;
  P.curr = curr;
  for (int i = 0; i < 8; ++i) { P.bias[i] = bias[i]; P.pk[i] = pk[i]; }
  P.audio_bf = audio_bf;
  for (int i = 0; i < 6; ++i) P.hr[i] = hr[i];
  P.ybuf = ybuf;
  P.hbot = hbot;
  P.arrv = arrv;
  P.gof = gof;
  P.out = (float*)d_out;
  P.rmask = R - 1;
  P.pmask = (R >> 1) - 1;

  void* args[] = { &P };
  (void)hipLaunchCooperativeKernel(reinterpret_cast<void*>(dancer_main),
                                   dim3(NWG), dim3(NTHR), args, 0, stream);
}

// Round 6
// 24068.654 us; speedup vs baseline: 2.3396x; 2.2989x over previous
//
#include <hip/hip_runtime.h>
#include <hip/hip_bf16.h>
#include <hip/hip_cooperative_groups.h>

namespace cg = cooperative_groups;

typedef __bf16 bf16;
typedef __bf16 bf16x8 __attribute__((ext_vector_type(8)));
typedef float  floatx4 __attribute__((ext_vector_type(4)));
typedef unsigned int uint32;

#define NB   64      // batch
#define NT   240     // timesteps
#define NDIM 512     // audio feature dim
#define NU   1024    // LSTM units
#define NOUT 75      // motion dim
#define NWG  64
#define NTHR 1024

// ring slot strides (elements)
#define HSLOT (64 * 1024)
#define YW    80
#define YSLOT (64 * YW)
#define BW    528
#define BSLOT (64 * BW)

struct Params {
  const float* curr;      // [64,75]
  const float* bias[8];   // enc1,enc2,enc3,fc,dec1,dec2,dec3,out
  const bf16*  pk[8];     // packed weights (B-fragment layout)
  const bf16*  audio_bf;  // [64, 240*512] bf16
  bf16* hr[6];            // h rings [R][64][1024] (enc1..3, dec1..3)
  bf16* ybuf;             // [R][64][80]  (y feedback, cols 75..79 zero)
  bf16* hbot;             // [R][64][528] (_h bottleneck, cols 512..527 zeroed)
  uint32* arrv;           // [64*32] arrival flags (128B spaced)
  uint32* gof;            // go flag
  float* out;             // [64,240,75]
  int rmask;              // ring depth - 1
  int pmask;              // heavy-sync period - 1
};

__device__ __forceinline__ float sigmoidf_(float x) { return 1.f / (1.f + __expf(-x)); }

// ---- cache-friendly grid barrier (two-hop; best measured variant) ----
__device__ __forceinline__ void gbar(uint32* arrv, uint32* gof, uint32 sc, int w, int tid)
{
  asm volatile("s_waitcnt vmcnt(0)" ::: "memory");
  __syncthreads();
  if (w == 0) {
    if (tid == 0)
      __hip_atomic_store(&arrv[0], sc, __ATOMIC_RELAXED, __HIP_MEMORY_SCOPE_AGENT);
    if (tid < NWG) {
      int spin = 0;
      while (__hip_atomic_load(&arrv[tid * 32], __ATOMIC_RELAXED, __HIP_MEMORY_SCOPE_AGENT) < sc) {
        __builtin_amdgcn_s_sleep(1);
        if (++spin > (1 << 24)) break;
      }
    }
    __syncthreads();
    if (tid == 0)
      __hip_atomic_store(gof, sc, __ATOMIC_RELAXED, __HIP_MEMORY_SCOPE_AGENT);
  } else {
    if (tid == 0) {
      __hip_atomic_store(&arrv[w * 32], sc, __ATOMIC_RELAXED, __HIP_MEMORY_SCOPE_AGENT);
      int spin = 0;
      while (__hip_atomic_load(gof, __ATOMIC_RELAXED, __HIP_MEMORY_SCOPE_AGENT) < sc) {
        __builtin_amdgcn_s_sleep(1);
        if (++spin > (1 << 24)) break;
      }
    }
    __syncthreads();
  }
}

// One LSTM cell stage, DMA-pipelined.
// A = [p0 (B1) | p1 (B2-B1) | p2 (KTOT-B2)], widths mult of 8. WG w owns units
// [16w,16w+16). 16 waves = 4 gates (g=wid&3) x 4 M-splits (v=wid>>2, full K).
// K is processed in chunks of 128 (4 k-blocks). Per chunk: A-subtile (64x128,
// 16KB) + B-subtile (64 cols x 128, 16KB) staged into LDS via global_load_lds
// (32 x 1KB instructions, 2 per wave), triple-buffered, 2 chunks in flight,
// counted s_waitcnt vmcnt + raw s_barrier (NOT __syncthreads - that would
// drain vmcnt and kill the prefetch pipeline).
template<int ST0, int B1, int ST1, int B2, int ST2, int KTOT, int KREAL>
__device__ void lstm_cell(const bf16* __restrict__ p0, const bf16* __restrict__ p1,
                          const bf16* __restrict__ p2,
                          const bf16* __restrict__ pack, const float* __restrict__ bias,
                          bf16* __restrict__ hout, float (* __restrict__ cc)[16],
                          float (* __restrict__ zbuf)[64][16], bf16 (* __restrict__ hstage)[16],
                          char* __restrict__ cb0, char* __restrict__ cb1, char* __restrict__ cb2,
                          int w, int tid)
{
  const int lane = tid & 63, wid = tid >> 6;
  const int g = wid & 3, v = wid >> 2;
  const int lq = lane >> 4, lr = lane & 15;
  constexpr int NCH = KTOT / 128;

  // ---- DMA issue: 2 instructions per wave per chunk (32 total: 16 A + 16 B) ----
  // chunk LDS layout: [A: kb(4) x mt(4) x 1KB][B: kb(4) x gate(4) x 1KB]
  // (global_load_lds dest = wave-uniform base + lane*16; lane=(lq,lr) matches
  //  the MFMA fragment layout on the read side exactly)
  auto issue = [&](int J, char* bufp) {
    #pragma unroll
    for (int ii = 0; ii < 2; ++ii) {
      const int idx = 2 * wid + ii;          // 0..31, wave-uniform
      const int kb  = (idx >> 2) & 3;
      const int sel = idx & 3;
      if (idx < 16) {                        // A: rows 16*sel+lr, k = J*128+kb*32+lq*8
        int kq = J * 128 + kb * 32 + lq * 8;
        if constexpr (KREAL < KTOT) { if (kq >= KREAL) kq = B2; }   // tail: safe addr x 0-weight
        const int row = 16 * sel + lr;
        const bf16* src;
        if (kq < B1)      src = p0 + (size_t)row * ST0 + kq;
        else if (kq < B2) src = p1 + (size_t)row * ST1 + (kq - B1);
        else              src = p2 + (size_t)row * ST2 + (kq - B2);
        __builtin_amdgcn_global_load_lds((const uint32*)src,
            (uint32*)(bufp + (kb * 4 + sel) * 1024), 16, 0, 0);
      } else {                               // B: cols 1024*sel + 16w + lr, kq8 = J*16+kb*4+lq
        const int kq8 = J * 16 + kb * 4 + lq;
        const bf16* src = pack + ((size_t)kq8 * 4096 + 1024 * sel + 16 * w + lr) * 8;
        __builtin_amdgcn_global_load_lds((const uint32*)src,
            (uint32*)(bufp + 16384 + (kb * 4 + sel) * 1024), 16, 0, 0);
      }
    }
  };

  floatx4 c = {0.f, 0.f, 0.f, 0.f};
  auto compute = [&](const char* bufp) {
    #pragma unroll
    for (int kb = 0; kb < 4; ++kb) {
      bf16x8 af  = *(const bf16x8*)(bufp + (kb * 4 + v) * 1024 + lane * 16);
      bf16x8 bfr = *(const bf16x8*)(bufp + 16384 + (kb * 4 + g) * 1024 + lane * 16);
      c = __builtin_amdgcn_mfma_f32_16x16x32_bf16(af, bfr, c, 0, 0, 0);
    }
  };

  // entered post-gbar/post-__syncthreads: vmcnt==0, all waves past prior LDS use
  char *pA = cb0, *pB = cb1, *pC = cb2;
  issue(0, pA);
  issue(1, pB);
  for (int J = 0; J < NCH - 1; ++J) {
    asm volatile("s_waitcnt vmcnt(2)" ::: "memory");   // own 2 loads of chunk J done
    __builtin_amdgcn_s_barrier();                       // => ALL waves' chunk-J parts done
    asm volatile("" ::: "memory");                      // fence: no LDS read hoists above
    if (J + 2 < NCH) issue(J + 2, pC);                  // pC was computed at J-1: free
    compute(pA);
    char* t = pA; pA = pB; pB = pC; pC = t;
  }
  asm volatile("s_waitcnt vmcnt(0)" ::: "memory");
  __builtin_amdgcn_s_barrier();
  asm volatile("" ::: "memory");
  compute(pA);

  // z -> zbuf: wave (g,v) owns rows 16v + lq*4 + r, col lr (full-K, no reduce)
  #pragma unroll
  for (int r = 0; r < 4; ++r)
    zbuf[g][16 * v + lq * 4 + r][lr] = c[r];
  __syncthreads();
  // pointwise: 1024 threads = 64 rows x 16 units
  {
    const int m = tid >> 4, u = tid & 15;
    const int uc = 16 * w + u;
    const float zi = zbuf[0][m][u] + bias[uc];
    const float zf = zbuf[1][m][u] + bias[NU + uc];
    const float zg = zbuf[2][m][u] + bias[2 * NU + uc];
    const float zo = zbuf[3][m][u] + bias[3 * NU + uc];
    const float cold = cc[m][u];
    const float cn = sigmoidf_(zf) * cold + sigmoidf_(zi) * tanhf(zg);
    cc[m][u] = cn;
    hstage[m][u] = (bf16)(sigmoidf_(zo) * tanhf(cn));
  }
  __syncthreads();
  // agent-scope (write-through) dword stores so other XCDs see fresh data
  if (tid < 512) {
    const int m = tid >> 3, up = tid & 7;
    const uint32 vv = *(const uint32*)&hstage[m][2 * up];
    __hip_atomic_store((uint32*)(hout + (size_t)m * NU + 16 * w) + up, vv,
                       __ATOMIC_RELAXED, __HIP_MEMORY_SCOPE_AGENT);
  }
}

// Small GEMM (fc / out): z[64,NEFF] = A[64,1024] @ pack. 16 waves: v=wid&3 rows, s=wid>>2 K.
// 8 k-blocks/wave: weights preloaded, A 2-deep pipelined (small enough for regs).
template<int NEFF>
__device__ void gemm_small(const bf16* __restrict__ a, const bf16* __restrict__ pack,
                           float (* __restrict__ zbuf)[64][16], int w, int tid)
{
  const int lane = tid & 63, wid = tid >> 6;
  const int v = wid & 3, s = wid >> 2;
  const int lr = lane & 15, lq = lane >> 4;
  const int n0 = 16 * w;

  const bf16* wbase = pack + ((size_t)lq * NEFF + (n0 + lr)) * 8;

  bf16x8 wreg[8];
  #pragma unroll
  for (int i = 0; i < 8; ++i)
    wreg[i] = *(const bf16x8*)(wbase + (size_t)(s + 4 * i) * (4 * NEFF * 8));

  floatx4 c = {0.f,0.f,0.f,0.f};
  const bf16* ab = a + (size_t)(16 * v + lr) * NU;

  bf16x8 xa[2];
  xa[0] = *(const bf16x8*)(ab + s * 32 + lq * 8);
  #pragma unroll
  for (int i = 0; i < 8; ++i) {
    const int cur = i & 1, nxt = cur ^ 1;
    if (i + 1 < 8)
      xa[nxt] = *(const bf16x8*)(ab + (s + 4 * (i + 1)) * 32 + lq * 8);
    c = __builtin_amdgcn_mfma_f32_16x16x32_bf16(xa[cur], wreg[i], c, 0, 0, 0);
  }

  #pragma unroll
  for (int r = 0; r < 4; ++r) zbuf[s][16 * v + lq * 4 + r][lr] = c[r];
  __syncthreads();
}

extern "C" __global__ void __launch_bounds__(NTHR)
dancer_main(Params p)
{
  __shared__ __align__(16) char cbuf[3][32768];  // 96 KB DMA chunk buffers (A 16K + B 16K)
  __shared__ float zbuf[4][64][16];              // 16 KB gate exchange
  __shared__ float cst[6][64][16];               // 24 KB persistent c state
  __shared__ bf16  hstage[64][16];               // 2 KB h staging
  cg::grid_group grid = cg::this_grid();
  const int tid = threadIdx.x;
  const int w = blockIdx.x;
  const int gtid = w * NTHR + tid;
  const int rmask = p.rmask, pmask = p.pmask;

  // ---- init: zero flags, zero h ring slot 'rmask', ybuf slot 0 from curr,
  //      zero hbot junk cols (512..527, all slots), zero c ----
  if (tid == 0) {
    p.arrv[w * 32] = 0;
    if (w == 0) *p.gof = 0;
  }
  for (int i = gtid; i < 6 * NB * NU; i += NWG * NTHR) {
    const int b = i >> 16, off = i & 65535;
    p.hr[b][(size_t)rmask * HSLOT + off] = (bf16)0.f;
  }
  for (int i = gtid; i < NB * YW; i += NWG * NTHR) {
    const int m = i / YW, c = i - m * YW;
    p.ybuf[i] = (c < NOUT) ? (bf16)p.curr[m * NOUT + c] : (bf16)0.f;
  }
  for (int i = gtid; i < (rmask + 1) * NB * 16; i += NWG * NTHR) {
    const int slot = i >> 10, m = (i >> 4) & 63, cix = i & 15;
    p.hbot[(size_t)slot * BSLOT + (size_t)m * BW + 512 + cix] = (bf16)0.f;
  }
  for (int i = tid; i < 6 * 64 * 16; i += NTHR) (&cst[0][0][0])[i] = 0.f;
  __syncthreads();
  grid.sync();   // full fence once: init writes visible everywhere

  uint32 sc = 1;
  for (int t = 0; t < NT; ++t) {
    const int st_ = t & rmask;
    const int sp_ = (t - 1) & rmask;
    __syncthreads();  // protect zbuf/hstage/cbuf reuse against previous readers

    // enc1: A = [audio_t (512) | h_enc1(t-1) (1024)], K=1536 (12 chunks)
    lstm_cell<NT * NDIM, NDIM, NU, NDIM, NU, NDIM + NU, NDIM + NU>(
        p.audio_bf + t * NDIM, p.hr[0] + (size_t)sp_ * HSLOT, p.hr[0] + (size_t)sp_ * HSLOT,
        p.pk[0], p.bias[0], p.hr[0] + (size_t)st_ * HSLOT, cst[0], zbuf, &hstage[0],
        cbuf[0], cbuf[1], cbuf[2], w, tid);
    gbar(p.arrv, p.gof, sc++, w, tid);

    lstm_cell<NU, NU, NU, NU, NU, 2 * NU, 2 * NU>(
        p.hr[0] + (size_t)st_ * HSLOT, p.hr[1] + (size_t)sp_ * HSLOT, p.hr[1] + (size_t)sp_ * HSLOT,
        p.pk[1], p.bias[1], p.hr[1] + (size_t)st_ * HSLOT, cst[1], zbuf, &hstage[0],
        cbuf[0], cbuf[1], cbuf[2], w, tid);
    gbar(p.arrv, p.gof, sc++, w, tid);

    lstm_cell<NU, NU, NU, NU, NU, 2 * NU, 2 * NU>(
        p.hr[1] + (size_t)st_ * HSLOT, p.hr[2] + (size_t)sp_ * HSLOT, p.hr[2] + (size_t)sp_ * HSLOT,
        p.pk[2], p.bias[2], p.hr[2] + (size_t)st_ * HSLOT, cst[2], zbuf, &hstage[0],
        cbuf[0], cbuf[1], cbuf[2], w, tid);
    gbar(p.arrv, p.gof, sc++, w, tid);

    // fc: _h = tanh(h_enc3 @ fc_W + b) -> hbot slot t
    if (w < 32) {
      gemm_small<512>(p.hr[2] + (size_t)st_ * HSLOT, p.pk[3], zbuf, w, tid);
      const int m = tid >> 4, u = tid & 15;
      const float z = zbuf[0][m][u] + zbuf[1][m][u] + zbuf[2][m][u] + zbuf[3][m][u]
                      + p.bias[3][16 * w + u];
      hstage[m][u] = (bf16)tanhf(z);
      __syncthreads();
      if (tid < 512) {
        const int m2 = tid >> 3, up = tid & 7;
        const uint32 v = *(const uint32*)&hstage[m2][2 * up];
        __hip_atomic_store((uint32*)(p.hbot + (size_t)st_ * BSLOT + (size_t)m2 * BW + 16 * w) + up,
                           v, __ATOMIC_RELAXED, __HIP_MEMORY_SCOPE_AGENT);
      }
    }
    gbar(p.arrv, p.gof, sc++, w, tid);

    // dec1: A = [ybuf(t) (80) | hbot(t) (528) | h_dec1(t-1) (1024)],
    // K padded 1632->1664 (13 chunks); tail A clamped, tail B zero-packed
    lstm_cell<YW, YW, BW, YW + BW, NU, 1664, YW + BW + NU>(
        p.ybuf + (size_t)st_ * YSLOT, p.hbot + (size_t)st_ * BSLOT, p.hr[3] + (size_t)sp_ * HSLOT,
        p.pk[4], p.bias[4], p.hr[3] + (size_t)st_ * HSLOT, cst[3], zbuf, &hstage[0],
        cbuf[0], cbuf[1], cbuf[2], w, tid);
    gbar(p.arrv, p.gof, sc++, w, tid);

    lstm_cell<NU, NU, NU, NU, NU, 2 * NU, 2 * NU>(
        p.hr[3] + (size_t)st_ * HSLOT, p.hr[4] + (size_t)sp_ * HSLOT, p.hr[4] + (size_t)sp_ * HSLOT,
        p.pk[5], p.bias[5], p.hr[4] + (size_t)st_ * HSLOT, cst[4], zbuf, &hstage[0],
        cbuf[0], cbuf[1], cbuf[2], w, tid);
    gbar(p.arrv, p.gof, sc++, w, tid);

    lstm_cell<NU, NU, NU, NU, NU, 2 * NU, 2 * NU>(
        p.hr[4] + (size_t)st_ * HSLOT, p.hr[5] + (size_t)sp_ * HSLOT, p.hr[5] + (size_t)sp_ * HSLOT,
        p.pk[6], p.bias[6], p.hr[5] + (size_t)st_ * HSLOT, cst[5], zbuf, &hstage[0],
        cbuf[0], cbuf[1], cbuf[2], w, tid);
    gbar(p.arrv, p.gof, sc++, w, tid);

    // out: y = elu(h_dec3 @ out_W + b) -> d_out and ybuf slot t+1 (no barrier:
    // covered by next step's chain before dec1 reads it)
    if (w < 5) {
      gemm_small<80>(p.hr[5] + (size_t)st_ * HSLOT, p.pk[7], zbuf, w, tid);
      const int m = tid >> 4, u = tid & 15;
      const int n = 16 * w + u;
      float y = 0.f;
      if (n < NOUT) {
        const float z = zbuf[0][m][u] + zbuf[1][m][u] + zbuf[2][m][u] + zbuf[3][m][u]
                        + p.bias[7][n];
        y = (z > 0.f) ? z : (__expf(z) - 1.f);
        p.out[(m * NT + t) * NOUT + n] = y;
      }
      hstage[m][u] = (bf16)y;
      __syncthreads();
      if (tid < 512) {
        const int m2 = tid >> 3, up = tid & 7;
        const uint32 v = *(const uint32*)&hstage[m2][2 * up];
        const size_t sn = (size_t)((t + 1) & rmask) * YSLOT;
        __hip_atomic_store((uint32*)(p.ybuf + sn + (size_t)m2 * YW + 16 * w) + up,
                           v, __ATOMIC_RELAXED, __HIP_MEMORY_SCOPE_AGENT);
      }
    }
    // periodic full sync: flush any cached ring lines before slot reuse
    if ((t & pmask) == pmask) grid.sync();
  }
}

// ---- pre-kernels ----

__global__ void pack_w(const float* __restrict__ Wx, const float* __restrict__ Wh,
                       int Kx, int KhStart, int Keff, int N, int Neff,
                       bf16* __restrict__ dst)
{
  const int idx = blockIdx.x * blockDim.x + threadIdx.x;
  const int nkb = Keff >> 3;
  const int total = nkb * Neff;
  if (idx >= total) return;
  const int kb = idx / Neff;
  const int n  = idx - kb * Neff;
  bf16x8 o;
  #pragma unroll
  for (int j = 0; j < 8; ++j) {
    const int k = kb * 8 + j;
    float v = 0.f;
    if (n < N) {
      if (k < Kx) v = Wx[(size_t)k * N + n];
      else if (k >= KhStart) v = Wh[(size_t)(k - KhStart) * N + n];
    }
    o[j] = (bf16)v;
  }
  *(bf16x8*)(dst + ((size_t)kb * Neff + n) * 8) = o;
}

// dec1: rows 0..74 = Wx[0..74] (y), 75..79 = 0, 80..591 = Wx[75..586] (_h),
//       592..607 = 0, 608..1631 = Wh, 1632..1663 = 0 (chunk pad). K=1664, N=4096.
__global__ void pack_dec1(const float* __restrict__ Wx, const float* __restrict__ Wh,
                          bf16* __restrict__ dst)
{
  const int idx = blockIdx.x * blockDim.x + threadIdx.x;
  const int total = (1664 >> 3) * 4096;
  if (idx >= total) return;
  const int kb = idx >> 12;
  const int n  = idx & 4095;
  bf16x8 o;
  #pragma unroll
  for (int j = 0; j < 8; ++j) {
    const int k = kb * 8 + j;
    float v = 0.f;
    if (k < 75)                    v = Wx[(size_t)k * 4096 + n];
    else if (k >= 80 && k < 592)   v = Wx[(size_t)(k - 5) * 4096 + n];
    else if (k >= 608 && k < 1632) v = Wh[(size_t)(k - 608) * 4096 + n];
    o[j] = (bf16)v;
  }
  *(bf16x8*)(dst + ((size_t)kb * 4096 + n) * 8) = o;
}

__global__ void cvt_bf16(const float* __restrict__ src, bf16* __restrict__ dst, int n)
{
  const int i = blockIdx.x * blockDim.x + threadIdx.x;
  if (i < n) dst[i] = (bf16)src[i];
}

extern "C" void kernel_launch(void* const* d_in, const int* in_sizes, int n_in,
                              void* d_out, int out_size, void* d_ws, size_t ws_size,
                              hipStream_t stream)
{
  (void)in_sizes; (void)n_in; (void)out_size;

  const float* audio = (const float*)d_in[0];
  const float* curr  = (const float*)d_in[1];
  const float* Wp[8][2] = {
    { (const float*)d_in[2],  (const float*)d_in[3]  },  // enc1
    { (const float*)d_in[5],  (const float*)d_in[6]  },  // enc2
    { (const float*)d_in[8],  (const float*)d_in[9]  },  // enc3
    { (const float*)d_in[11], nullptr                },  // fc
    { (const float*)d_in[13], (const float*)d_in[14] },  // dec1
    { (const float*)d_in[16], (const float*)d_in[17] },  // dec2
    { (const float*)d_in[19], (const float*)d_in[20] },  // dec3
    { (const float*)d_in[22], nullptr                },  // out
  };
  const float* bias[8] = {
    (const float*)d_in[4],  (const float*)d_in[7],  (const float*)d_in[10],
    (const float*)d_in[12], (const float*)d_in[15], (const float*)d_in[18],
    (const float*)d_in[21], (const float*)d_in[23],
  };

  // {Kx, KhStart, Keff, N, Neff}; dec1 handled by pack_dec1 (K padded to 1664)
  const int geo[8][5] = {
    { 512,  512,  1536, 4096, 4096 },  // enc1
    { 1024, 1024, 2048, 4096, 4096 },  // enc2
    { 1024, 1024, 2048, 4096, 4096 },  // enc3
    { 1024, 1024, 1024, 512,  512  },  // fc
    { 0,    0,    1664, 4096, 4096 },  // dec1 (custom, padded)
    { 1024, 1024, 2048, 4096, 4096 },  // dec2
    { 1024, 1024, 2048, 4096, 4096 },  // dec3
    { 1024, 1024, 1024, 75,   80   },  // out
  };

  char* ws = (char*)d_ws;
  size_t off = 0;
  auto take = [&](size_t bytes) -> char* {
    char* p = ws + off;
    off = (off + bytes + 255) & ~(size_t)255;
    return p;
  };

  bf16* audio_bf = (bf16*)take((size_t)NB * NT * NDIM * 2);
  bf16* pk[8];
  for (int i = 0; i < 8; ++i) pk[i] = (bf16*)take((size_t)geo[i][2] * geo[i][4] * 2);
  uint32* arrv = (uint32*)take(64 * 32 * sizeof(uint32));
  uint32* gof  = (uint32*)take(256);

  // pick ring depth that fits ws
  const size_t slot_bytes = (size_t)6 * HSLOT * 2 + (size_t)YSLOT * 2 + (size_t)BSLOT * 2 + 4096;
  int R = 32;
  while (R > 4 && off + (size_t)R * slot_bytes + (1 << 20) > ws_size) R >>= 1;

  bf16* hr[6];
  for (int i = 0; i < 6; ++i) hr[i] = (bf16*)take((size_t)R * HSLOT * 2);
  bf16* ybuf = (bf16*)take((size_t)R * YSLOT * 2);
  bf16* hbot = (bf16*)take((size_t)R * BSLOT * 2);

  {
    const int n = NB * NT * NDIM;
    cvt_bf16<<<(n + 255) / 256, 256, 0, stream>>>(audio, audio_bf, n);
  }
  for (int i = 0; i < 8; ++i) {
    if (i == 4) {
      const int total = (1664 >> 3) * 4096;
      pack_dec1<<<(total + 255) / 256, 256, 0, stream>>>(Wp[4][0], Wp[4][1], pk[4]);
    } else {
      const int total = (geo[i][2] >> 3) * geo[i][4];
      pack_w<<<(total + 255) / 256, 256, 0, stream>>>(
          Wp[i][0], Wp[i][1], geo[i][0], geo[i][1], geo[i][2], geo[i][3], geo[i][4], pk[i]);
    }
  }

  Params P;
  P.curr = curr;
  for (int i = 0; i < 8; ++i) { P.bias[i] = bias[i]; P.pk[i] = pk[i]; }
  P.audio_bf = audio_bf;
  for (int i = 0; i < 6; ++i) P.hr[i] = hr[i];
  P.ybuf = ybuf;
  P.hbot = hbot;
  P.arrv = arrv;
  P.gof = gof;
  P.out = (float*)d_out;
  P.rmask = R - 1;
  P.pmask = (R >> 1) - 1;

  void* args[] = { &P };
  (void)hipLaunchCooperativeKernel(reinterpret_cast<void*>(dancer_main),
                                   dim3(NWG), dim3(NTHR), args, 0, stream);
}